// Round 7
// baseline (59.912 us; speedup 1.0000x reference)
//
#include <hip/hip_runtime.h>
#include <hip/hip_bf16.h>

// Local (trunked) attention, MI355X gfx950.
// B=1, H=16, N=16384, d=64 fp32; 32-query trunks x 128-key window, pad_left=48.
// Block = 6 waves = 6 consecutive trunks of one head; 288-row K/V window union
// staged once to LDS as f16 (row-major, XOR-swizzled). K read as ds_read_b128
// column slices; V read as scalar u16 B-fragments (proven round-3 path).
// Swapped-QK^T 32x32 MFMA structure, per-lane softmax, P normalized IN the
// pack (lane's col=query only holds in the S^T phase; O-phase lanes are
// d-columns, so 1/sum must be applied before the P re-layout).

typedef _Float16 f16x8 __attribute__((ext_vector_type(8)));
typedef float f32x16 __attribute__((ext_vector_type(16)));
typedef unsigned int u32;
typedef u32 u32x4 __attribute__((ext_vector_type(4)));

#define NSEQ   16384
#define DHEAD  64
#define LOG2E  1.44269504088896340736f
#define TRB    6                 // trunks per block
#define BQ     (TRB * 32)        // 192 queries per block
#define WROWS  (BQ + 96)         // 288 staged rows
#define RSTR   128               // LDS row stride (bytes, 64 f16)
#define KBYTES (WROWS * RSTR)    // 36864
#define BPH    86                // blocks per head: ceil(512/6)

__device__ __forceinline__ int swz(int r) {
  return ((r & 7) << 4) | ((r & 8) << 3);   // permute 16B-slots within a row
}

__device__ __forceinline__ u32 pk2(float a, float b) {
  auto h2 = __builtin_amdgcn_cvt_pkrtz(a, b);
  return __builtin_bit_cast(u32, h2);
}

__device__ __forceinline__ void plswap(u32& a, u32& b) {
#if __has_builtin(__builtin_amdgcn_permlane32_swap)
  typedef u32 u32x2 __attribute__((ext_vector_type(2)));
  u32x2 r = __builtin_amdgcn_permlane32_swap(a, b, false, false);
  a = r[0]; b = r[1];
#else
  const int hi = (threadIdx.x & 63) >> 5;
  u32 sa = (u32)__shfl_xor((int)a, 32);
  u32 sb = (u32)__shfl_xor((int)b, 32);
  u32 na = hi ? sb : a;
  u32 nb = hi ? b : sa;
  a = na; b = nb;
#endif
}

// Stage 288 rows x 64 f32 -> LDS f16 (row-major + XOR swizzle). 384 thr, 6 it.
__device__ __forceinline__ void stage288(const float* __restrict__ src, int grow0,
                                         char* __restrict__ dst, int tid) {
  const int rsub = tid >> 3;          // 0..47
  const int c8   = (tid & 7) * 8;     // f32 col
  #pragma unroll
  for (int it = 0; it < 6; ++it) {
    const int r = it * 48 + rsub;
    const int g = min(max(grow0 + r, 0), NSEQ - 1);   // clamp; masked in S
    const float* p = src + (size_t)g * DHEAD + c8;
    const float4 a = *reinterpret_cast<const float4*>(p);
    const float4 b = *reinterpret_cast<const float4*>(p + 4);
    const u32x4 w = {pk2(a.x, a.y), pk2(a.z, a.w), pk2(b.x, b.y), pk2(b.z, b.w)};
    *reinterpret_cast<u32x4*>(dst + ((r * RSTR + c8 * 2) ^ swz(r))) = w;
  }
}

__global__ __launch_bounds__(384, 3) void local_attn_kernel(
    const float* __restrict__ q, const float* __restrict__ k,
    const float* __restrict__ v, float* __restrict__ out) {
  __shared__ __align__(128) char smem[2 * KBYTES];   // 73,728 B: K then V
  char* const Kc = smem;
  char* const Vc = smem + KBYTES;

  const int tid  = threadIdx.x;
  const int wave = tid >> 6;
  const int lane = tid & 63;
  const int l31  = lane & 31;
  const int hi   = lane >> 5;

  int bid = blockIdx.x;
  bid = (bid & 7) * 172 + (bid >> 3);      // XCD swizzle (1376 = 8*172, bijective)
  const int h   = bid / BPH;
  const int bb  = bid - h * BPH;
  const int q0b = bb * BQ;
  const int kg0 = q0b - 48;                // global row of LDS row 0
  const int q0  = q0b + wave * 32;         // this wave's trunk (may be >= NSEQ)
  const int kvb = wave * 32;               // wave's local key base in LDS

  const float* __restrict__ qh = q + (size_t)h * NSEQ * DHEAD;
  const float* __restrict__ kh = k + (size_t)h * NSEQ * DHEAD;
  const float* __restrict__ vh = v + (size_t)h * NSEQ * DHEAD;

  // ---- Q raw loads issued before staging (latency hides under stage) ----
  const int qrow = min(q0 + l31, NSEQ - 1);
  float4 qr[4][2];
  #pragma unroll
  for (int ks = 0; ks < 4; ++ks) {
    const float* p = qh + (size_t)qrow * DHEAD + ks * 16 + hi * 8;
    qr[ks][0] = *reinterpret_cast<const float4*>(p);
    qr[ks][1] = *reinterpret_cast<const float4*>(p + 4);
  }

  // ---- cooperative K/V staging ------------------------------------------
  stage288(kh, kg0, Kc, tid);
  stage288(vh, kg0, Vc, tid);
  __syncthreads();

  if (q0 >= NSEQ) return;                  // ragged tail waves (last block)

  // ---- S^T = K Q^T  (128 keys x 32 queries) -----------------------------
  // D[m=key][n=q]: col = lane&31 = q, row = (r&3)+8*(r>>2)+4*hi (+32*kt)
  f32x16 sacc[4] = {};
  #pragma unroll
  for (int ks = 0; ks < 4; ++ks) {
    f16x8 qf;
    qf[0] = (_Float16)(qr[ks][0].x * LOG2E); qf[1] = (_Float16)(qr[ks][0].y * LOG2E);
    qf[2] = (_Float16)(qr[ks][0].z * LOG2E); qf[3] = (_Float16)(qr[ks][0].w * LOG2E);
    qf[4] = (_Float16)(qr[ks][1].x * LOG2E); qf[5] = (_Float16)(qr[ks][1].y * LOG2E);
    qf[6] = (_Float16)(qr[ks][1].z * LOG2E); qf[7] = (_Float16)(qr[ks][1].w * LOG2E);
    #pragma unroll
    for (int kt = 0; kt < 4; ++kt) {
      const int row = kvb + kt * 32 + l31;
      const f16x8 kf = *reinterpret_cast<const f16x8*>(
          Kc + ((row * RSTR + (ks * 16 + hi * 8) * 2) ^ swz(row)));
      sacc[kt] = __builtin_amdgcn_mfma_f32_32x32x16_f16(kf, qf, sacc[kt], 0, 0, 0);
    }
  }

  // ---- mask invalid keys (edge trunks only) -----------------------------
  if (q0 < 48 || q0 > NSEQ - 80) {
    #pragma unroll
    for (int kt = 0; kt < 4; ++kt)
      #pragma unroll
      for (int r = 0; r < 16; ++r) {
        const int key = (q0 - 48) + kt * 32 + (r & 3) + 8 * (r >> 2) + 4 * hi;
        if ((unsigned)key >= (unsigned)NSEQ) sacc[kt][r] = -1e30f;
      }
  }

  // ---- per-lane softmax over 128 keys (base-2 domain) -------------------
  float mx = -1e30f;
  #pragma unroll
  for (int kt = 0; kt < 4; ++kt)
    #pragma unroll
    for (int r = 0; r < 16; ++r) mx = fmaxf(mx, sacc[kt][r]);
  mx = fmaxf(mx, __shfl_xor(mx, 32));
  float sum = 0.f;
  #pragma unroll
  for (int kt = 0; kt < 4; ++kt)
    #pragma unroll
    for (int r = 0; r < 16; ++r) {
      const float p = exp2f(sacc[kt][r] - mx);
      sacc[kt][r] = p;
      sum += p;
    }
  sum += __shfl_xor(sum, 32);
  const float inv = 1.0f / sum;

  // ---- P -> A-fragments in-register, NORMALIZED here --------------------
  // (inv is per-query only while lane col = query; after PV the lane index
  //  means d-column, so 1/sum cannot be applied at the store.)
  f16x8 pa[4][2];
  #pragma unroll
  for (int kt = 0; kt < 4; ++kt) {
    u32 pk[8];
    #pragma unroll
    for (int c = 0; c < 8; ++c)
      pk[c] = pk2(sacc[kt][2 * c] * inv, sacc[kt][2 * c + 1] * inv);
    plswap(pk[0], pk[2]); plswap(pk[1], pk[3]);
    plswap(pk[4], pk[6]); plswap(pk[5], pk[7]);
    union { f16x8 f; u32 u[4]; } f0, f1;
    f0.u[0] = pk[0]; f0.u[1] = pk[1]; f0.u[2] = pk[2]; f0.u[3] = pk[3];
    f1.u[0] = pk[4]; f1.u[1] = pk[5]; f1.u[2] = pk[6]; f1.u[3] = pk[7];
    pa[kt][0] = f0.f;
    pa[kt][1] = f1.f;
  }

  // ---- O = P V  (32 x 64), V scalar reads from swizzled LDS -------------
  f32x16 oacc[2] = {};
  #pragma unroll
  for (int kt = 0; kt < 4; ++kt) {
    #pragma unroll
    for (int b = 0; b < 2; ++b) {
      const int rbase = kvb + kt * 32 + b * 16 + hi * 8;
      f16x8 bv0, bv1;
      #pragma unroll
      for (int j = 0; j < 8; ++j) {
        const int row = rbase + j;
        const int a0 = (row * RSTR + l31 * 2) ^ swz(row);
        const int a1 = (row * RSTR + l31 * 2 + 64) ^ swz(row);
        bv0[j] = *reinterpret_cast<const _Float16*>(Vc + a0);
        bv1[j] = *reinterpret_cast<const _Float16*>(Vc + a1);
      }
      oacc[0] = __builtin_amdgcn_mfma_f32_32x32x16_f16(pa[kt][b], bv0, oacc[0], 0, 0, 0);
      oacc[1] = __builtin_amdgcn_mfma_f32_32x32x16_f16(pa[kt][b], bv1, oacc[1], 0, 0, 0);
    }
  }

  // ---- store O (row = query = crow(r,hi); col = lane = d) ---------------
  float* __restrict__ oh = out + (size_t)h * NSEQ * DHEAD;
  #pragma unroll
  for (int r = 0; r < 16; ++r) {
    const int row = q0 + (r & 3) + 8 * (r >> 2) + 4 * hi;
    float* po = oh + (size_t)row * DHEAD + l31;
    po[0]  = oacc[0][r];
    po[32] = oacc[1][r];
  }
}

extern "C" void kernel_launch(void* const* d_in, const int* in_sizes, int n_in,
                              void* d_out, int out_size, void* d_ws, size_t ws_size,
                              hipStream_t stream) {
  const float* q = (const float*)d_in[0];
  const float* k = (const float*)d_in[1];
  const float* v = (const float*)d_in[2];
  float* out = (float*)d_out;
  dim3 grid(16 * BPH), block(384);   // 1376 blocks, 6 trunks per block
  hipLaunchKernelGGL(local_attn_kernel, grid, block, 0, stream, q, k, v, out);
}

// Round 8
// 44.376 us; speedup vs baseline: 1.3501x; 1.3501x over previous
//
#include <hip/hip_runtime.h>
#include <hip/hip_bf16.h>

// Local (trunked) attention, MI355X gfx950.
// B=1, H=16, N=16384, d=64 fp32; 32-query trunks x 128-key window, pad_left=48.
// Block = 4 waves = 4 consecutive trunks of one head; 224-row K/V window union
// staged once to LDS as f16. K: row-major XOR-swizzled, ds_read_b128 slices.
// V: 4x16-subtiled layout consumed via ds_read_b64_tr_b16 hardware transpose
// (per-lane base + lane*8; immediate offsets walk subtiles). Swapped-QK^T
// 32x32 MFMA structure, per-lane softmax, P normalized in the in-register
// pack (cvt_pkrtz + permlane32_swap).

typedef _Float16 f16x8 __attribute__((ext_vector_type(8)));
typedef _Float16 f16x4 __attribute__((ext_vector_type(4)));
typedef float f32x16 __attribute__((ext_vector_type(16)));
typedef unsigned int u32;
typedef u32 u32x4 __attribute__((ext_vector_type(4)));

#define NSEQ   16384
#define DHEAD  64
#define LOG2E  1.44269504088896340736f
#define TRB    4                 // trunks per block
#define BQ     (TRB * 32)        // 128 queries per block
#define WROWS  (BQ + 96)         // 224 staged rows
#define RSTR   128               // K row stride (bytes, 64 f16)
#define KBYTES (WROWS * RSTR)    // 28672 (K); V same size in subtiled form

__device__ __forceinline__ int swz(int r) {
  return ((r & 7) << 4) | ((r & 8) << 3);   // permute 16B-slots within a row
}

__device__ __forceinline__ u32 pk2(float a, float b) {
  auto h2 = __builtin_amdgcn_cvt_pkrtz(a, b);
  return __builtin_bit_cast(u32, h2);
}

__device__ __forceinline__ void plswap(u32& a, u32& b) {
#if __has_builtin(__builtin_amdgcn_permlane32_swap)
  typedef u32 u32x2 __attribute__((ext_vector_type(2)));
  u32x2 r = __builtin_amdgcn_permlane32_swap(a, b, false, false);
  a = r[0]; b = r[1];
#else
  const int hi = (threadIdx.x & 63) >> 5;
  u32 sa = (u32)__shfl_xor((int)a, 32);
  u32 sb = (u32)__shfl_xor((int)b, 32);
  u32 na = hi ? sb : a;
  u32 nb = hi ? b : sa;
  a = na; b = nb;
#endif
}

// 4 transpose-reads; va = subtile-block base + lane*8 (per-lane!).
// Delivers b0 = {t0 (keys kk&4==0), t1 (kk&4==1)} for d 0..31,
//          b1 = {t2, t3} for d 32..63.
__device__ __forceinline__ void tr4(u32 va, f16x4& t0, f16x4& t1, f16x4& t2, f16x4& t3) {
  asm volatile("ds_read_b64_tr_b16 %0, %4 offset:0\n\t"
               "ds_read_b64_tr_b16 %1, %4 offset:1024\n\t"
               "ds_read_b64_tr_b16 %2, %4 offset:512\n\t"
               "ds_read_b64_tr_b16 %3, %4 offset:1536\n\t"
               "s_waitcnt lgkmcnt(0)"
               : "=&v"(t0), "=&v"(t1), "=&v"(t2), "=&v"(t3)
               : "v"(va));
  __builtin_amdgcn_sched_barrier(0);
}

// Stage 224 rows x 64 f32 -> LDS f16, K layout (row-major + XOR swizzle).
__device__ __forceinline__ void stageK(const float* __restrict__ src, int grow0,
                                       char* __restrict__ dst, int tid) {
  const int rsub = tid >> 3;          // 0..31
  const int c8   = (tid & 7) * 8;     // f32 col
  #pragma unroll
  for (int it = 0; it < 7; ++it) {
    const int r = it * 32 + rsub;
    const int g = min(max(grow0 + r, 0), NSEQ - 1);   // clamp; masked in S
    const float* p = src + (size_t)g * DHEAD + c8;
    const float4 a = *reinterpret_cast<const float4*>(p);
    const float4 b = *reinterpret_cast<const float4*>(p + 4);
    const u32x4 w = {pk2(a.x, a.y), pk2(a.z, a.w), pk2(b.x, b.y), pk2(b.z, b.w)};
    *reinterpret_cast<u32x4*>(dst + ((r * RSTR + c8 * 2) ^ swz(r))) = w;
  }
}

// Stage V into 4x16 subtiles matching tr4's delivery:
// within each 2KB key-16 block, subtile idx =
//   ((kk>>2)&1)*8 + (dh>>1)*4 + ((kk>>3)&1)*2 + (dh&1),  kk=r&15, dh=d>>4.
__device__ __forceinline__ void stageV(const float* __restrict__ src, int grow0,
                                       char* __restrict__ dst, int tid) {
  const int rsub = tid >> 3;
  const int c8   = (tid & 7) * 8;
  const int dh   = c8 >> 4;
  #pragma unroll
  for (int it = 0; it < 7; ++it) {
    const int r = it * 32 + rsub;
    const int g = min(max(grow0 + r, 0), NSEQ - 1);
    const float* p = src + (size_t)g * DHEAD + c8;
    const float4 a = *reinterpret_cast<const float4*>(p);
    const float4 b = *reinterpret_cast<const float4*>(p + 4);
    const u32x4 w = {pk2(a.x, a.y), pk2(a.z, a.w), pk2(b.x, b.y), pk2(b.z, b.w)};
    const int idx = ((r >> 2) & 1) * 8 + (dh >> 1) * 4 + ((r >> 3) & 1) * 2 + (dh & 1);
    const int addr = (r >> 4) * 2048 + idx * 128 + (r & 3) * 32 + (c8 & 15) * 2;
    *reinterpret_cast<u32x4*>(dst + addr) = w;
  }
}

__global__ __launch_bounds__(256, 2) void local_attn_kernel(
    const float* __restrict__ q, const float* __restrict__ k,
    const float* __restrict__ v, float* __restrict__ out) {
  __shared__ __align__(128) char smem[2 * KBYTES];   // 57,344 B: K then V
  char* const Kc = smem;
  char* const Vc = smem + KBYTES;

  const int tid  = threadIdx.x;
  const int wave = tid >> 6;
  const int lane = tid & 63;
  const int l31  = lane & 31;
  const int hi   = lane >> 5;

  int bid = blockIdx.x;
  bid = (bid & 7) * 256 + (bid >> 3);      // XCD swizzle (2048 % 8 == 0)
  const int h   = bid >> 7;                // head
  const int q0b = (bid & 127) << 7;        // block's first query row
  const int kg0 = q0b - 48;                // global row of LDS row 0
  const int q0  = q0b + wave * 32;         // this wave's trunk
  const int kvb = wave * 32;               // wave's local key base in LDS

  const float* __restrict__ qh = q + (size_t)h * NSEQ * DHEAD;
  const float* __restrict__ kh = k + (size_t)h * NSEQ * DHEAD;
  const float* __restrict__ vh = v + (size_t)h * NSEQ * DHEAD;

  // ---- Q raw loads issued before staging (latency hides under stage) ----
  float4 qr[4][2];
  #pragma unroll
  for (int ks = 0; ks < 4; ++ks) {
    const float* p = qh + (size_t)(q0 + l31) * DHEAD + ks * 16 + hi * 8;
    qr[ks][0] = *reinterpret_cast<const float4*>(p);
    qr[ks][1] = *reinterpret_cast<const float4*>(p + 4);
  }

  // ---- cooperative K/V staging ------------------------------------------
  stageK(kh, kg0, Kc, tid);
  stageV(vh, kg0, Vc, tid);
  __syncthreads();

  // ---- S^T = K Q^T  (128 keys x 32 queries) -----------------------------
  // D[m=key][n=q]: col = lane&31 = q, row = (r&3)+8*(r>>2)+4*hi (+32*kt)
  f32x16 sacc[4] = {};
  #pragma unroll
  for (int ks = 0; ks < 4; ++ks) {
    f16x8 qf;
    qf[0] = (_Float16)(qr[ks][0].x * LOG2E); qf[1] = (_Float16)(qr[ks][0].y * LOG2E);
    qf[2] = (_Float16)(qr[ks][0].z * LOG2E); qf[3] = (_Float16)(qr[ks][0].w * LOG2E);
    qf[4] = (_Float16)(qr[ks][1].x * LOG2E); qf[5] = (_Float16)(qr[ks][1].y * LOG2E);
    qf[6] = (_Float16)(qr[ks][1].z * LOG2E); qf[7] = (_Float16)(qr[ks][1].w * LOG2E);
    #pragma unroll
    for (int kt = 0; kt < 4; ++kt) {
      const int row = kvb + kt * 32 + l31;
      const f16x8 kf = *reinterpret_cast<const f16x8*>(
          Kc + ((row * RSTR + (ks * 16 + hi * 8) * 2) ^ swz(row)));
      sacc[kt] = __builtin_amdgcn_mfma_f32_32x32x16_f16(kf, qf, sacc[kt], 0, 0, 0);
    }
  }

  // ---- mask invalid keys (edge trunks only) -----------------------------
  if (q0 < 48 || q0 > NSEQ - 80) {
    #pragma unroll
    for (int kt = 0; kt < 4; ++kt)
      #pragma unroll
      for (int r = 0; r < 16; ++r) {
        const int key = (q0 - 48) + kt * 32 + (r & 3) + 8 * (r >> 2) + 4 * hi;
        if ((unsigned)key >= (unsigned)NSEQ) sacc[kt][r] = -1e30f;
      }
  }

  // ---- per-lane softmax over 128 keys (base-2 domain) -------------------
  float mx = -1e30f;
  #pragma unroll
  for (int kt = 0; kt < 4; ++kt)
    #pragma unroll
    for (int r = 0; r < 16; ++r) mx = fmaxf(mx, sacc[kt][r]);
  mx = fmaxf(mx, __shfl_xor(mx, 32));
  float sum = 0.f;
  #pragma unroll
  for (int kt = 0; kt < 4; ++kt)
    #pragma unroll
    for (int r = 0; r < 16; ++r) {
      const float p = exp2f(sacc[kt][r] - mx);
      sacc[kt][r] = p;
      sum += p;
    }
  sum += __shfl_xor(sum, 32);
  const float inv = 1.0f / sum;

  // ---- P -> A-fragments in-register, normalized HERE --------------------
  // (lane col = query only in the S^T phase; after PV lanes mean d-columns)
  f16x8 pa[4][2];
  #pragma unroll
  for (int kt = 0; kt < 4; ++kt) {
    u32 pk[8];
    #pragma unroll
    for (int c = 0; c < 8; ++c)
      pk[c] = pk2(sacc[kt][2 * c] * inv, sacc[kt][2 * c + 1] * inv);
    plswap(pk[0], pk[2]); plswap(pk[1], pk[3]);
    plswap(pk[4], pk[6]); plswap(pk[5], pk[7]);
    union { f16x8 f; u32 u[4]; } f0, f1;
    f0.u[0] = pk[0]; f0.u[1] = pk[1]; f0.u[2] = pk[2]; f0.u[3] = pk[3];
    f1.u[0] = pk[4]; f1.u[1] = pk[5]; f1.u[2] = pk[6]; f1.u[3] = pk[7];
    pa[kt][0] = f0.f;
    pa[kt][1] = f1.f;
  }

  // ---- O = P V  (32 x 64), V via hardware transpose reads ---------------
  const u32 vb = (u32)(size_t)Vc + (u32)(lane * 8);
  f32x16 oacc[2] = {};
  #pragma unroll
  for (int kt = 0; kt < 4; ++kt) {
    #pragma unroll
    for (int b = 0; b < 2; ++b) {
      const u32 va = vb + (u32)((2 * (wave + kt) + b) * 2048);
      f16x4 t0, t1, t2, t3;
      tr4(va, t0, t1, t2, t3);
      union { f16x8 f; f16x4 h[2]; } b0, b1;
      b0.h[0] = t0; b0.h[1] = t1;
      b1.h[0] = t2; b1.h[1] = t3;
      oacc[0] = __builtin_amdgcn_mfma_f32_32x32x16_f16(pa[kt][b], b0.f, oacc[0], 0, 0, 0);
      oacc[1] = __builtin_amdgcn_mfma_f32_32x32x16_f16(pa[kt][b], b1.f, oacc[1], 0, 0, 0);
    }
  }

  // ---- store O (row = query = crow(r,hi); col = lane = d) ---------------
  float* __restrict__ oh = out + (size_t)h * NSEQ * DHEAD;
  #pragma unroll
  for (int r = 0; r < 16; ++r) {
    const int row = q0 + (r & 3) + 8 * (r >> 2) + 4 * hi;
    float* po = oh + (size_t)row * DHEAD + l31;
    po[0]  = oacc[0][r];
    po[32] = oacc[1][r];
  }
}

extern "C" void kernel_launch(void* const* d_in, const int* in_sizes, int n_in,
                              void* d_out, int out_size, void* d_ws, size_t ws_size,
                              hipStream_t stream) {
  const float* q = (const float*)d_in[0];
  const float* k = (const float*)d_in[1];
  const float* v = (const float*)d_in[2];
  float* out = (float*)d_out;
  dim3 grid(2048), block(256);   // block = 4 consecutive trunks of one head
  hipLaunchKernelGGL(local_attn_kernel, grid, block, 0, stream, q, k, v, out);
}